// Round 1
// baseline (1508.766 us; speedup 1.0000x reference)
//
#include <hip/hip_runtime.h>
#include <hip/hip_bf16.h>

#define NN 16384
#define DD 300
#define DP 320
#define RR 10
#define BB 1024
#define KK 64
#define NCH 32   // column/row chunks (N / 512)

typedef __attribute__((ext_vector_type(8))) short s8v;   // 8 bf16 (4 VGPRs)
typedef __attribute__((ext_vector_type(4))) float f4v;   // MFMA accumulator

// sorted-descending top-10 insert; all static indices (no scratch spill)
__device__ __forceinline__ void topk_insert(float (&lst)[10], float v) {
    if (v > lst[9]) {
        float cur = v;
        #pragma unroll
        for (int q = 0; q < 10; ++q) {
            float a  = lst[q];
            bool  sw = cur > a;
            lst[q] = sw ? cur : a;
            cur    = sw ? a : cur;
        }
    }
}

// ---------------------------------------------------------------------------
// Kernel 1: Householder tower + L2 normalize + bf16 cast (padded to 320).
// One wave per row; block = 4 waves.
// ---------------------------------------------------------------------------
__global__ __launch_bounds__(256) void tower_kernel(
        const float* __restrict__ feat, const float* __restrict__ vs,
        __hip_bfloat16* __restrict__ out) {
    __shared__ float vsh[RR * DD];
    const int tid = threadIdx.x;
    for (int i = tid; i < RR * DD; i += 256) vsh[i] = vs[i];
    __syncthreads();

    const int lane = tid & 63;
    const int wave = tid >> 6;
    const int row  = blockIdx.x * 4 + wave;

    float h[5];
    #pragma unroll
    for (int j = 0; j < 5; ++j) {
        int d = lane + 64 * j;
        h[j] = (d < DD) ? feat[(size_t)row * DD + d] : 0.f;
    }

    #pragma unroll
    for (int r = 0; r < RR; ++r) {
        float vl[5];
        float hv = 0.f, vv = 0.f;
        #pragma unroll
        for (int j = 0; j < 5; ++j) {
            int d = lane + 64 * j;
            float v = (d < DD) ? vsh[r * DD + d] : 0.f;
            vl[j] = v;
            hv += h[j] * v;
            vv += v * v;
        }
        #pragma unroll
        for (int o = 32; o; o >>= 1) {
            hv += __shfl_xor(hv, o);
            vv += __shfl_xor(vv, o);
        }
        float coef = hv / vv;
        #pragma unroll
        for (int j = 0; j < 5; ++j) h[j] -= coef * vl[j];
    }

    float nn = 0.f;
    #pragma unroll
    for (int j = 0; j < 5; ++j) nn += h[j] * h[j];
    #pragma unroll
    for (int o = 32; o; o >>= 1) nn += __shfl_xor(nn, o);
    float scale = 1.f / fmaxf(sqrtf(nn), 1e-12f);

    #pragma unroll
    for (int j = 0; j < 5; ++j) {
        int d = lane + 64 * j;
        float val = (d < DD) ? h[j] * scale : 0.f;   // zero-pad 300..319
        out[(size_t)row * DP + d] = __float2bfloat16(val);
    }
}

// ---------------------------------------------------------------------------
// Kernel 2: 512x512 sim region per block (grid 32x32). 16 inner 128x128 MFMA
// tiles (bf16 16x16x32, K=320). Per-row / per-col top-10 kept in LDS across
// the region; written as candidates [N][32][10].
// ---------------------------------------------------------------------------
__global__ __launch_bounds__(512) void sim_topk_kernel(
        const __hip_bfloat16* __restrict__ A,   // src_hn [N][320]
        const __hip_bfloat16* __restrict__ Bm,  // tgt_hn [N][320]
        float* __restrict__ rowcand,            // [N][NCH][10]
        float* __restrict__ colcand) {          // [N][NCH][10]
    __shared__ __hip_bfloat16 Asub[128][72];    // +8 bf16 pad: 144B stride
    __shared__ __hip_bfloat16 Bsub[128][72];
    __shared__ float simt[128][132];            // +4 pad
    __shared__ float rowlist[512][10];
    __shared__ float collist[512][10];

    const int tid  = threadIdx.x;
    const int lane = tid & 63;
    const int w    = tid >> 6;   // 0..7
    const int wr   = w >> 2;     // 0..1  (M direction, 64 rows each)
    const int wc   = w & 3;      // 0..3  (N direction, 32 cols each)
    const int i0   = blockIdx.y * 512;
    const int j0   = blockIdx.x * 512;

    for (int q = tid; q < 512 * 10; q += 512) {
        (&rowlist[0][0])[q] = -1e30f;
        (&collist[0][0])[q] = -1e30f;
    }
    __syncthreads();

    for (int ti = 0; ti < 4; ++ti) {
        for (int tj = 0; tj < 4; ++tj) {
            f4v acc[4][2];
            #pragma unroll
            for (int m = 0; m < 4; ++m)
                #pragma unroll
                for (int n = 0; n < 2; ++n)
                    acc[m][n] = (f4v){0.f, 0.f, 0.f, 0.f};

            const __hip_bfloat16* Ab = A  + (size_t)(i0 + ti * 128) * DP;
            const __hip_bfloat16* Bb = Bm + (size_t)(j0 + tj * 128) * DP;

            for (int kb = 0; kb < 5; ++kb) {
                __syncthreads();   // prior k-step's fragment reads done
                // stage 128x64 of A and B: 1024 16B-chunks each, 512 threads
                {
                    const int cid0 = tid, cid1 = tid + 512;
                    const int r0 = cid0 >> 3, k0 = cid0 & 7;
                    const int r1 = cid1 >> 3, k1 = cid1 & 7;
                    int4 va0 = *reinterpret_cast<const int4*>(Ab + (size_t)r0 * DP + kb * 64 + k0 * 8);
                    int4 vb0 = *reinterpret_cast<const int4*>(Bb + (size_t)r0 * DP + kb * 64 + k0 * 8);
                    int4 va1 = *reinterpret_cast<const int4*>(Ab + (size_t)r1 * DP + kb * 64 + k1 * 8);
                    int4 vb1 = *reinterpret_cast<const int4*>(Bb + (size_t)r1 * DP + kb * 64 + k1 * 8);
                    *reinterpret_cast<int4*>(&Asub[r0][k0 * 8]) = va0;
                    *reinterpret_cast<int4*>(&Bsub[r0][k0 * 8]) = vb0;
                    *reinterpret_cast<int4*>(&Asub[r1][k1 * 8]) = va1;
                    *reinterpret_cast<int4*>(&Bsub[r1][k1 * 8]) = vb1;
                }
                __syncthreads();
                #pragma unroll
                for (int ks = 0; ks < 2; ++ks) {
                    s8v af[4], bfv[2];
                    const int koff = ks * 32 + (lane >> 4) * 8;
                    #pragma unroll
                    for (int m = 0; m < 4; ++m)
                        af[m] = *reinterpret_cast<const s8v*>(&Asub[wr * 64 + m * 16 + (lane & 15)][koff]);
                    #pragma unroll
                    for (int n = 0; n < 2; ++n)
                        bfv[n] = *reinterpret_cast<const s8v*>(&Bsub[wc * 32 + n * 16 + (lane & 15)][koff]);
                    #pragma unroll
                    for (int m = 0; m < 4; ++m)
                        #pragma unroll
                        for (int n = 0; n < 2; ++n)
                            acc[m][n] = __builtin_amdgcn_mfma_f32_16x16x32_bf16(
                                af[m], bfv[n], acc[m][n], 0, 0, 0);
                }
            }
            __syncthreads();
            // scatter accumulators to the fp32 sim tile
            // C/D layout: col = lane&15, row = (lane>>4)*4 + reg  [m89-verified]
            #pragma unroll
            for (int m = 0; m < 4; ++m)
                #pragma unroll
                for (int n = 0; n < 2; ++n)
                    #pragma unroll
                    for (int r = 0; r < 4; ++r)
                        simt[wr * 64 + m * 16 + (lane >> 4) * 4 + r]
                            [wc * 32 + n * 16 + (lane & 15)] = acc[m][n][r];
            __syncthreads();

            // top-10 maintenance: waves 0-1 scan rows, waves 2-3 scan cols
            if (tid < 128) {
                const int rloc = tid;
                float* gl = rowlist[ti * 128 + rloc];
                float lst[10];
                #pragma unroll
                for (int q = 0; q < 10; ++q) lst[q] = gl[q];
                for (int c4 = 0; c4 < 128; c4 += 4) {
                    float4 v = *reinterpret_cast<const float4*>(&simt[rloc][c4]);
                    topk_insert(lst, v.x); topk_insert(lst, v.y);
                    topk_insert(lst, v.z); topk_insert(lst, v.w);
                }
                #pragma unroll
                for (int q = 0; q < 10; ++q) gl[q] = lst[q];
            } else if (tid < 256) {
                const int cloc = tid - 128;
                float* gl = collist[tj * 128 + cloc];
                float lst[10];
                #pragma unroll
                for (int q = 0; q < 10; ++q) lst[q] = gl[q];
                for (int rr = 0; rr < 128; ++rr)
                    topk_insert(lst, simt[rr][cloc]);
                #pragma unroll
                for (int q = 0; q < 10; ++q) gl[q] = lst[q];
            }
            __syncthreads();
        }
    }

    // flush candidates
    for (int q = tid; q < 512 * 10; q += 512) {
        int rloc = q / 10, qq = q % 10;
        rowcand[((size_t)(i0 + rloc) * NCH + blockIdx.x) * 10 + qq] = rowlist[rloc][qq];
        colcand[((size_t)(j0 + rloc) * NCH + blockIdx.y) * 10 + qq] = collist[rloc][qq];
    }
}

// ---------------------------------------------------------------------------
// Kernel 3: merge 32 chunks x 10 candidates -> mean(top10) = rt / rs
// ---------------------------------------------------------------------------
__global__ __launch_bounds__(256) void reduce_topk(
        const float* __restrict__ rowcand, const float* __restrict__ colcand,
        float* __restrict__ rt, float* __restrict__ rs) {
    const int t = blockIdx.x * 256 + threadIdx.x;   // 0 .. 2N-1
    const bool isRow = (t < NN);
    const int  row   = isRow ? t : t - NN;
    const float* src = isRow ? rowcand : colcand;

    float lst[10];
    #pragma unroll
    for (int q = 0; q < 10; ++q) lst[q] = -1e30f;

    const float4* p = reinterpret_cast<const float4*>(src + (size_t)row * (NCH * 10));
    for (int c = 0; c < NCH * 10 / 4; ++c) {
        float4 v = p[c];
        topk_insert(lst, v.x); topk_insert(lst, v.y);
        topk_insert(lst, v.z); topk_insert(lst, v.w);
    }
    float s = 0.f;
    #pragma unroll
    for (int q = 0; q < 10; ++q) s += lst[q];
    s *= 0.1f;
    if (isRow) rt[row] = s; else rs[row] = s;
}

// ---------------------------------------------------------------------------
// Kernel 4: gathered dots + CSLS logits. One block per b; wave per k-slice.
// ---------------------------------------------------------------------------
__global__ __launch_bounds__(256) void logits_kernel(
        const __hip_bfloat16* __restrict__ srcH, const __hip_bfloat16* __restrict__ tgtH,
        const int* __restrict__ sidx, const int* __restrict__ tidx,
        const float* __restrict__ rt, const float* __restrict__ rs,
        float* __restrict__ out) {
    const int b    = blockIdx.x;
    const int lane = threadIdx.x & 63;
    const int w    = threadIdx.x >> 6;

    const int s0 = sidx[b * KK];
    const int t0 = tidx[b * KK];
    float ps[5], pt[5];
    #pragma unroll
    for (int j = 0; j < 5; ++j) {
        int d = lane + 64 * j;
        ps[j] = __bfloat162float(srcH[(size_t)s0 * DP + d]);
        pt[j] = __bfloat162float(tgtH[(size_t)t0 * DP + d]);
    }
    const float rt_s0 = rt[s0];
    const float rs_t0 = rs[t0];

    for (int kk = w; kk < KK; kk += 4) {
        const int it = tidx[b * KK + kk];
        const int is = sidx[b * KK + kk];
        float a = 0.f, c = 0.f;
        #pragma unroll
        for (int j = 0; j < 5; ++j) {
            int d = lane + 64 * j;
            a += ps[j] * __bfloat162float(tgtH[(size_t)it * DP + d]);
            c += pt[j] * __bfloat162float(srcH[(size_t)is * DP + d]);
        }
        #pragma unroll
        for (int o = 32; o; o >>= 1) {
            a += __shfl_xor(a, o);
            c += __shfl_xor(c, o);
        }
        if (lane == 0) {
            out[b * KK + kk]           = 2.f * a - rt_s0 - rs[it];
            out[BB * KK + b * KK + kk] = 2.f * c - rs_t0 - rt[is];
        }
    }
}

// ---------------------------------------------------------------------------
extern "C" void kernel_launch(void* const* d_in, const int* in_sizes, int n_in,
                              void* d_out, int out_size, void* d_ws, size_t ws_size,
                              hipStream_t stream) {
    const float* nf_src = (const float*)d_in[0];
    const float* nf_tgt = (const float*)d_in[1];
    const int*   sidx   = (const int*)d_in[2];
    const int*   tidx   = (const int*)d_in[3];
    const float* svs    = (const float*)d_in[4];
    const float* tvs    = (const float*)d_in[5];

    char* ws = (char*)d_ws;
    const size_t SZ_H    = (size_t)NN * DP * 2;            // 10,485,760 (bf16)
    const size_t SZ_CAND = (size_t)NN * NCH * 10 * 4;      // 20,971,520
    __hip_bfloat16* srcH = (__hip_bfloat16*)ws;
    __hip_bfloat16* tgtH = (__hip_bfloat16*)(ws + SZ_H);
    float* rowcand = (float*)(ws + 2 * SZ_H);
    float* colcand = (float*)(ws + 2 * SZ_H + SZ_CAND);
    float* rt      = (float*)(ws + 2 * SZ_H + 2 * SZ_CAND);
    float* rs      = (float*)(ws + 2 * SZ_H + 2 * SZ_CAND + (size_t)NN * 4);
    // total ws use: 63,045,632 bytes

    tower_kernel<<<NN / 4, 256, 0, stream>>>(nf_src, svs, srcH);
    tower_kernel<<<NN / 4, 256, 0, stream>>>(nf_tgt, tvs, tgtH);
    sim_topk_kernel<<<dim3(NCH, NCH), 512, 0, stream>>>(srcH, tgtH, rowcand, colcand);
    reduce_topk<<<(2 * NN) / 256, 256, 0, stream>>>(rowcand, colcand, rt, rs);
    logits_kernel<<<BB, 256, 0, stream>>>(srcH, tgtH, sidx, tidx, rt, rs, (float*)d_out);
}

// Round 2
// 840.987 us; speedup vs baseline: 1.7940x; 1.7940x over previous
//
#include <hip/hip_runtime.h>
#include <hip/hip_bf16.h>

#define NN 16384
#define DD 300
#define DP 320
#define RR 10
#define BB 1024
#define KK 64
#define NCH 32   // column/row chunks (N / 512)

typedef __attribute__((ext_vector_type(8))) short s8v;            // 8 bf16
typedef __attribute__((ext_vector_type(8))) unsigned short u16x8; // 8 bf16 bits
typedef __attribute__((ext_vector_type(4))) float f4v;            // MFMA acc

// sorted-descending top-10 insert
__device__ __forceinline__ void topk_insert(float (&lst)[10], float v) {
    if (v > lst[9]) {
        float cur = v;
        #pragma unroll
        for (int q = 0; q < 10; ++q) {
            float a  = lst[q];
            bool  sw = cur > a;
            lst[q] = sw ? cur : a;
            cur    = sw ? a : cur;
        }
    }
}

__device__ __forceinline__ float bf16bits_to_f32(unsigned short b) {
    return __uint_as_float(((unsigned)b) << 16);
}

// ---------------------------------------------------------------------------
// Kernel 1: Householder tower + L2 normalize + bf16 cast (padded to 320).
// ---------------------------------------------------------------------------
__global__ __launch_bounds__(256) void tower_kernel(
        const float* __restrict__ feat, const float* __restrict__ vs,
        __hip_bfloat16* __restrict__ out) {
    __shared__ float vsh[RR * DD];
    const int tid = threadIdx.x;
    for (int i = tid; i < RR * DD; i += 256) vsh[i] = vs[i];
    __syncthreads();

    const int lane = tid & 63;
    const int wave = tid >> 6;
    const int row  = blockIdx.x * 4 + wave;

    float h[5];
    #pragma unroll
    for (int j = 0; j < 5; ++j) {
        int d = lane + 64 * j;
        h[j] = (d < DD) ? feat[(size_t)row * DD + d] : 0.f;
    }

    #pragma unroll
    for (int r = 0; r < RR; ++r) {
        float vl[5];
        float hv = 0.f, vv = 0.f;
        #pragma unroll
        for (int j = 0; j < 5; ++j) {
            int d = lane + 64 * j;
            float v = (d < DD) ? vsh[r * DD + d] : 0.f;
            vl[j] = v;
            hv += h[j] * v;
            vv += v * v;
        }
        #pragma unroll
        for (int o = 32; o; o >>= 1) {
            hv += __shfl_xor(hv, o);
            vv += __shfl_xor(vv, o);
        }
        float coef = hv / vv;
        #pragma unroll
        for (int j = 0; j < 5; ++j) h[j] -= coef * vl[j];
    }

    float nn = 0.f;
    #pragma unroll
    for (int j = 0; j < 5; ++j) nn += h[j] * h[j];
    #pragma unroll
    for (int o = 32; o; o >>= 1) nn += __shfl_xor(nn, o);
    float scale = 1.f / fmaxf(sqrtf(nn), 1e-12f);

    #pragma unroll
    for (int j = 0; j < 5; ++j) {
        int d = lane + 64 * j;
        float val = (d < DD) ? h[j] * scale : 0.f;
        out[(size_t)row * DP + d] = __float2bfloat16(val);
    }
}

// ---------------------------------------------------------------------------
// Kernel 2: 512x512 sim region per block (grid 32x32), 16 inner 128x128 MFMA
// tiles. LDS diet (76 KB -> 2 blocks/CU): staging unioned with a bf16
// XOR-swizzled sim tile; scans use batched LDS loads.
// ---------------------------------------------------------------------------
__global__ __launch_bounds__(512, 4) void sim_topk_kernel(
        const __hip_bfloat16* __restrict__ A,   // src_hn [N][320]
        const __hip_bfloat16* __restrict__ Bm,  // tgt_hn [N][320]
        float* __restrict__ rowcand,            // [N][NCH][10]
        float* __restrict__ colcand) {          // [N][NCH][10]
    // union: staging (2 x [128][72] bf16 = 36864 B)  |  simt ([128] rows x
    // 256 B of swizzled bf16 = 32768 B). Temporally disjoint within a tile.
    __shared__ __align__(16) char u_lds[36864];
    __shared__ float rowlist[512][10];
    __shared__ float collist[512][10];

    __hip_bfloat16* Asub = (__hip_bfloat16*)u_lds;             // [128][72]
    __hip_bfloat16* Bsub = (__hip_bfloat16*)(u_lds + 18432);   // [128][72]
    char* simt = u_lds;   // bf16 [128][128]: byte = row*256 + ((col>>3)^(row&15))*16 + (col&7)*2

    const int tid  = threadIdx.x;
    const int lane = tid & 63;
    const int w    = tid >> 6;   // 0..7
    const int wr   = w >> 2;     // 0..1  (M direction, 64 rows each)
    const int wc   = w & 3;      // 0..3  (N direction, 32 cols each)
    const int i0   = blockIdx.y * 512;
    const int j0   = blockIdx.x * 512;

    for (int q = tid; q < 512 * 10; q += 512) {
        (&rowlist[0][0])[q] = -1e30f;
        (&collist[0][0])[q] = -1e30f;
    }
    __syncthreads();

    for (int ti = 0; ti < 4; ++ti) {
        for (int tj = 0; tj < 4; ++tj) {
            f4v acc[4][2];
            #pragma unroll
            for (int m = 0; m < 4; ++m)
                #pragma unroll
                for (int n = 0; n < 2; ++n)
                    acc[m][n] = (f4v){0.f, 0.f, 0.f, 0.f};

            const __hip_bfloat16* Ab = A  + (size_t)(i0 + ti * 128) * DP;
            const __hip_bfloat16* Bb = Bm + (size_t)(j0 + tj * 128) * DP;

            for (int kb = 0; kb < 5; ++kb) {
                __syncthreads();   // prior phase (frag reads / scan) done
                {
                    const int r0 = tid >> 3,          k0 = tid & 7;
                    const int r1 = (tid + 512) >> 3,  k1 = tid & 7;
                    int4 va0 = *reinterpret_cast<const int4*>(Ab + (size_t)r0 * DP + kb * 64 + k0 * 8);
                    int4 vb0 = *reinterpret_cast<const int4*>(Bb + (size_t)r0 * DP + kb * 64 + k0 * 8);
                    int4 va1 = *reinterpret_cast<const int4*>(Ab + (size_t)r1 * DP + kb * 64 + k1 * 8);
                    int4 vb1 = *reinterpret_cast<const int4*>(Bb + (size_t)r1 * DP + kb * 64 + k1 * 8);
                    *reinterpret_cast<int4*>(Asub + r0 * 72 + k0 * 8) = va0;
                    *reinterpret_cast<int4*>(Bsub + r0 * 72 + k0 * 8) = vb0;
                    *reinterpret_cast<int4*>(Asub + r1 * 72 + k1 * 8) = va1;
                    *reinterpret_cast<int4*>(Bsub + r1 * 72 + k1 * 8) = vb1;
                }
                __syncthreads();
                #pragma unroll
                for (int ks = 0; ks < 2; ++ks) {
                    s8v af[4], bfv[2];
                    const int koff = ks * 32 + (lane >> 4) * 8;
                    #pragma unroll
                    for (int m = 0; m < 4; ++m)
                        af[m] = *reinterpret_cast<const s8v*>(Asub + (wr * 64 + m * 16 + (lane & 15)) * 72 + koff);
                    #pragma unroll
                    for (int n = 0; n < 2; ++n)
                        bfv[n] = *reinterpret_cast<const s8v*>(Bsub + (wc * 32 + n * 16 + (lane & 15)) * 72 + koff);
                    #pragma unroll
                    for (int m = 0; m < 4; ++m)
                        #pragma unroll
                        for (int n = 0; n < 2; ++n)
                            acc[m][n] = __builtin_amdgcn_mfma_f32_16x16x32_bf16(
                                af[m], bfv[n], acc[m][n], 0, 0, 0);
                }
            }
            __syncthreads();   // all frag reads done before simt overwrites staging

            // scatter acc -> swizzled bf16 simt
            // C/D layout: col = lane&15, row = (lane>>4)*4 + reg
            #pragma unroll
            for (int m = 0; m < 4; ++m) {
                const int row = wr * 64 + m * 16 + (lane >> 4) * 4;
                #pragma unroll
                for (int n = 0; n < 2; ++n) {
                    const int col = wc * 32 + n * 16 + (lane & 15);
                    #pragma unroll
                    for (int r = 0; r < 4; ++r) {
                        const int rr = row + r;
                        __hip_bfloat16 b = __float2bfloat16(acc[m][n][r]);
                        *reinterpret_cast<__hip_bfloat16*>(
                            simt + rr * 256 + (((col >> 3) ^ (rr & 15)) << 4) + (col & 7) * 2) = b;
                    }
                }
            }
            __syncthreads();

            // scans: waves 0-1 rows, waves 2-3 cols (value-only, any order ok)
            if (tid < 128) {
                const int rloc = tid;
                const char* rbase = simt + rloc * 256;
                const int sw = rloc & 15;
                float* gl = rowlist[ti * 128 + rloc];
                float lst[10];
                #pragma unroll
                for (int q = 0; q < 10; ++q) lst[q] = gl[q];
                #pragma unroll
                for (int ub = 0; ub < 16; ub += 4) {
                    u16x8 q0 = *reinterpret_cast<const u16x8*>(rbase + (((ub + 0) ^ sw) << 4));
                    u16x8 q1 = *reinterpret_cast<const u16x8*>(rbase + (((ub + 1) ^ sw) << 4));
                    u16x8 q2 = *reinterpret_cast<const u16x8*>(rbase + (((ub + 2) ^ sw) << 4));
                    u16x8 q3 = *reinterpret_cast<const u16x8*>(rbase + (((ub + 3) ^ sw) << 4));
                    #pragma unroll
                    for (int e = 0; e < 8; ++e) {
                        topk_insert(lst, bf16bits_to_f32(q0[e]));
                        topk_insert(lst, bf16bits_to_f32(q1[e]));
                        topk_insert(lst, bf16bits_to_f32(q2[e]));
                        topk_insert(lst, bf16bits_to_f32(q3[e]));
                    }
                }
                #pragma unroll
                for (int q = 0; q < 10; ++q) gl[q] = lst[q];
            } else if (tid < 256) {
                const int cloc = tid - 128;
                const int u_log = cloc >> 3;
                const int off   = (cloc & 7) * 2;
                float* gl = collist[tj * 128 + cloc];
                float lst[10];
                #pragma unroll
                for (int q = 0; q < 10; ++q) lst[q] = gl[q];
                for (int rb = 0; rb < 128; rb += 8) {
                    unsigned short v[8];
                    #pragma unroll
                    for (int j = 0; j < 8; ++j) {
                        const int r = rb + j;
                        v[j] = *reinterpret_cast<const unsigned short*>(
                            simt + r * 256 + (((u_log ^ (r & 15)) << 4)) + off);
                    }
                    #pragma unroll
                    for (int j = 0; j < 8; ++j)
                        topk_insert(lst, bf16bits_to_f32(v[j]));
                }
                #pragma unroll
                for (int q = 0; q < 10; ++q) gl[q] = lst[q];
            }
            __syncthreads();
        }
    }

    // flush candidates
    for (int q = tid; q < 512 * 10; q += 512) {
        int rloc = q / 10, qq = q % 10;
        rowcand[((size_t)(i0 + rloc) * NCH + blockIdx.x) * 10 + qq] = rowlist[rloc][qq];
        colcand[((size_t)(j0 + rloc) * NCH + blockIdx.y) * 10 + qq] = collist[rloc][qq];
    }
}

// ---------------------------------------------------------------------------
// Kernel 3: merge 32 chunks x 10 candidates -> mean(top10) = rt / rs
// ---------------------------------------------------------------------------
__global__ __launch_bounds__(256) void reduce_topk(
        const float* __restrict__ rowcand, const float* __restrict__ colcand,
        float* __restrict__ rt, float* __restrict__ rs) {
    const int t = blockIdx.x * 256 + threadIdx.x;   // 0 .. 2N-1
    const bool isRow = (t < NN);
    const int  row   = isRow ? t : t - NN;
    const float* src = isRow ? rowcand : colcand;

    float lst[10];
    #pragma unroll
    for (int q = 0; q < 10; ++q) lst[q] = -1e30f;

    const float4* p = reinterpret_cast<const float4*>(src + (size_t)row * (NCH * 10));
    for (int c = 0; c < NCH * 10 / 4; ++c) {
        float4 v = p[c];
        topk_insert(lst, v.x); topk_insert(lst, v.y);
        topk_insert(lst, v.z); topk_insert(lst, v.w);
    }
    float s = 0.f;
    #pragma unroll
    for (int q = 0; q < 10; ++q) s += lst[q];
    s *= 0.1f;
    if (isRow) rt[row] = s; else rs[row] = s;
}

// ---------------------------------------------------------------------------
// Kernel 4: gathered dots + CSLS logits.
// ---------------------------------------------------------------------------
__global__ __launch_bounds__(256) void logits_kernel(
        const __hip_bfloat16* __restrict__ srcH, const __hip_bfloat16* __restrict__ tgtH,
        const int* __restrict__ sidx, const int* __restrict__ tidx,
        const float* __restrict__ rt, const float* __restrict__ rs,
        float* __restrict__ out) {
    const int b    = blockIdx.x;
    const int lane = threadIdx.x & 63;
    const int w    = threadIdx.x >> 6;

    const int s0 = sidx[b * KK];
    const int t0 = tidx[b * KK];
    float ps[5], pt[5];
    #pragma unroll
    for (int j = 0; j < 5; ++j) {
        int d = lane + 64 * j;
        ps[j] = __bfloat162float(srcH[(size_t)s0 * DP + d]);
        pt[j] = __bfloat162float(tgtH[(size_t)t0 * DP + d]);
    }
    const float rt_s0 = rt[s0];
    const float rs_t0 = rs[t0];

    for (int kk = w; kk < KK; kk += 4) {
        const int it = tidx[b * KK + kk];
        const int is = sidx[b * KK + kk];
        float a = 0.f, c = 0.f;
        #pragma unroll
        for (int j = 0; j < 5; ++j) {
            int d = lane + 64 * j;
            a += ps[j] * __bfloat162float(tgtH[(size_t)it * DP + d]);
            c += pt[j] * __bfloat162float(srcH[(size_t)is * DP + d]);
        }
        #pragma unroll
        for (int o = 32; o; o >>= 1) {
            a += __shfl_xor(a, o);
            c += __shfl_xor(c, o);
        }
        if (lane == 0) {
            out[b * KK + kk]           = 2.f * a - rt_s0 - rs[it];
            out[BB * KK + b * KK + kk] = 2.f * c - rs_t0 - rt[is];
        }
    }
}

// ---------------------------------------------------------------------------
extern "C" void kernel_launch(void* const* d_in, const int* in_sizes, int n_in,
                              void* d_out, int out_size, void* d_ws, size_t ws_size,
                              hipStream_t stream) {
    const float* nf_src = (const float*)d_in[0];
    const float* nf_tgt = (const float*)d_in[1];
    const int*   sidx   = (const int*)d_in[2];
    const int*   tidx   = (const int*)d_in[3];
    const float* svs    = (const float*)d_in[4];
    const float* tvs    = (const float*)d_in[5];

    char* ws = (char*)d_ws;
    const size_t SZ_H    = (size_t)NN * DP * 2;            // bf16 features
    const size_t SZ_CAND = (size_t)NN * NCH * 10 * 4;
    __hip_bfloat16* srcH = (__hip_bfloat16*)ws;
    __hip_bfloat16* tgtH = (__hip_bfloat16*)(ws + SZ_H);
    float* rowcand = (float*)(ws + 2 * SZ_H);
    float* colcand = (float*)(ws + 2 * SZ_H + SZ_CAND);
    float* rt      = (float*)(ws + 2 * SZ_H + 2 * SZ_CAND);
    float* rs      = (float*)(ws + 2 * SZ_H + 2 * SZ_CAND + (size_t)NN * 4);

    tower_kernel<<<NN / 4, 256, 0, stream>>>(nf_src, svs, srcH);
    tower_kernel<<<NN / 4, 256, 0, stream>>>(nf_tgt, tvs, tgtH);
    sim_topk_kernel<<<dim3(NCH, NCH), 512, 0, stream>>>(srcH, tgtH, rowcand, colcand);
    reduce_topk<<<(2 * NN) / 256, 256, 0, stream>>>(rowcand, colcand, rt, rs);
    logits_kernel<<<BB, 256, 0, stream>>>(srcH, tgtH, sidx, tidx, rt, rs, (float*)d_out);
}